// Round 8
// baseline (246.853 us; speedup 1.0000x reference)
//
#include <hip/hip_runtime.h>
#include <hip/hip_bf16.h>

typedef __bf16 bf16x8 __attribute__((ext_vector_type(8)));
typedef float  f32x4  __attribute__((ext_vector_type(4)));

// LDS layout (bytes). Act buffers: 116 rows x 128 bf16 (user0 rows 0-51, user1 64-115),
// XOR-swizzled 16B k-blocks. mfma A-reads span rows 0..127; rows 52-63/116-127 are
// garbage -> masked (garbage never crosses rows in A*B; outputs guarded by (row&63)<50).
#define W_OFF 0            // weight K-half: 128n x 64k bf16, swizzled (16384 B)
#define A_OFF 16384        // act buf A: x1 then a1 (29696 B)
#define X_OFF 46080        // act buf X: x, persists to pooling (29696 B)
#define SMALL 75776        // persistent small arrays (4608 B)
#define SMEM_TOTAL 80384   // -> 2 blocks/CU (160.77 KB of 160 KiB... 2*80384=160768<=163840)
#define WCHUNK 16384       // bf16 elems per full weight chunk in global
#define WHALF  8192        // bf16 elems per K-half

// ws layout (bytes): wprep(8 chunks) | Pi(bf16) | Pt | Pr | Pu | Pu2  (~36.6 MB)
#define WS_WPREP 0
#define WS_PI    262144
#define WS_PT    (WS_PI + 25600000)     // Pi: 100000*128 bf16
#define WS_PR    (WS_PT + 512000)       // Pt: 1000*128 fp32
#define WS_PU    (WS_PR + 3072)         // Pr: 6*128 fp32 (ne_b folded in)
#define WS_PU2   (WS_PU + 5120000)      // Pu: 10000*128 fp32

// ---------------- prep: fp32 [k][n] -> bf16 [chunk][khalf][n][swizzled k64] ----------
// chunks: 0-2 ne_w slices, 3 ne1_w, 4 att1_w[:128], 5 att2_w, 6 att1_w[128:], 7 lin_w[:128]
__global__ void prep_weights_kernel(const float* __restrict__ ne_w,
                                    const float* __restrict__ ne1_w,
                                    const float* __restrict__ att1_w,
                                    const float* __restrict__ att2_w,
                                    const float* __restrict__ lin_w,
                                    __hip_bfloat16* __restrict__ wout) {
  __shared__ float tile[64][65];
  const int bx = blockIdx.x;
  const int c = bx >> 2, kt = (bx >> 1) & 1, ntile = bx & 1;
  const float* src; int koff;
  if      (c < 3)  { src = ne_w;   koff = c * 128; }
  else if (c == 3) { src = ne1_w;  koff = 0; }
  else if (c == 4) { src = att1_w; koff = 0; }
  else if (c == 5) { src = att2_w; koff = 0; }
  else if (c == 6) { src = att1_w; koff = 128; }
  else             { src = lin_w;  koff = 0; }
  const int tx = threadIdx.x, ty = threadIdx.y;
#pragma unroll
  for (int r = 0; r < 16; ++r) {
    int k = kt * 64 + r * 4 + ty, n = ntile * 64 + tx;
    tile[r * 4 + ty][tx] = src[(koff + k) * 128 + n];   // coalesced over n
  }
  __syncthreads();
#pragma unroll
  for (int r = 0; r < 16; ++r) {
    int n = ntile * 64 + r * 4 + ty, k = kt * 64 + tx;  // chunk-local k in [0,128)
    int h = k >> 6, k64 = k & 63;
    int off = c * WCHUNK + h * WHALF + n * 64 + ((((k64 >> 3) ^ (n & 7))) << 3) + (k64 & 7);
    wout[off] = __float2bfloat16(tile[tx][r * 4 + ty]);
  }
}

// ---------------- helpers ----------------
__device__ __forceinline__ unsigned short bf_bits(float x) {
  return __builtin_bit_cast(unsigned short, __float2bfloat16(x));
}

// One K-half of a 128-K GEMM, 2 m16-tiles per wave. A from 16-blk-swizzled act rows,
// B from 8-blk-swizzled LDS half-chunk. Wave tile 32m x 64n.
__device__ __forceinline__ void mfma_half2(const __hip_bfloat16* sIn,
                                           const __hip_bfloat16* sWh,
                                           f32x4 acc[2][4], int h, int m32, int nh,
                                           int lane) {
  const int mr = lane & 15;
  const int kq = lane >> 4;            // 0..3
#pragma unroll
  for (int ks = 0; ks < 2; ++ks) {
    const int kb16 = h * 8 + ks * 4 + kq;           // logical 16B-block in full K
    const int aswz = ((kb16 ^ mr) << 3);
    bf16x8 a0 = *(const bf16x8*)(sIn + (m32 * 32 + mr) * 128 + aswz);
    bf16x8 a1 = *(const bf16x8*)(sIn + (m32 * 32 + 16 + mr) * 128 + aswz);
    const int swzb = (((ks * 4 + kq) ^ (mr & 7)) << 3);
#pragma unroll
    for (int nt = 0; nt < 4; ++nt) {
      const int n = nh * 64 + nt * 16 + mr;         // n&7 == mr&7 -> swzb valid
      bf16x8 b = *(const bf16x8*)(sWh + n * 64 + swzb);
      acc[0][nt] = __builtin_amdgcn_mfma_f32_16x16x32_bf16(a0, b, acc[0][nt], 0, 0, 0);
      acc[1][nt] = __builtin_amdgcn_mfma_f32_16x16x32_bf16(a1, b, acc[1][nt], 0, 0, 0);
    }
  }
}

// bias + optional per-user row-vector + relu + swizzled bf16 store ((row&63)<50 only)
__device__ __forceinline__ void epilogue2(f32x4 acc[2][4], const float* __restrict__ bias,
                                          const float* addvec, __hip_bfloat16* sOut,
                                          int m32, int nh, int lane) {
  const int mr = lane & 15;
  const int u = m32 >> 1;
#pragma unroll
  for (int mt = 0; mt < 2; ++mt) {
    const int rb = m32 * 32 + mt * 16 + ((lane >> 4) << 2);
#pragma unroll
    for (int nt = 0; nt < 4; ++nt) {
      const int col = nh * 64 + nt * 16 + mr;
      float bv = bias[col];
      if (addvec) bv += addvec[u * 128 + col];
      const int cblk = col >> 3, clo = col & 7;
#pragma unroll
      for (int r = 0; r < 4; ++r) {
        const int row = rb + r;
        if ((row & 63) < 50) {
          float v = fmaxf(acc[mt][nt][r] + bv, 0.0f);
          sOut[row * 128 + ((cblk ^ (row & 15)) << 3) + clo] = __float2bfloat16(v);
        }
      }
    }
  }
}

// ---------------- P-GEMM: P = table @ W_chunk (+opt bias), once per launch ----------
// 256 rows/block (4 tiles of 64 reusing one staged 32KB chunk).
// segs: Pi(i2e,c0,bf16 out) | Pt(t2e,c2) | Pr(r2e,c1,+ne_b) | Pu(u2e,c6) | Pu2(u2e,c7)
__global__ __launch_bounds__(512) void pgemm_kernel(
    const float* __restrict__ i2e, const float* __restrict__ r2e,
    const float* __restrict__ t2e, const float* __restrict__ u2e,
    const float* __restrict__ ne_b, const __hip_bfloat16* __restrict__ wprep,
    __hip_bfloat16* __restrict__ Pi, float* __restrict__ Pt, float* __restrict__ Pr,
    float* __restrict__ Pu, float* __restrict__ Pu2) {
  __shared__ __align__(16) __hip_bfloat16 sW[WCHUNK];
  __shared__ __align__(16) __hip_bfloat16 sA[64 * 128];
  const int tid = threadIdx.x, lane = tid & 63, wid = tid >> 6;
  const int m16 = wid & 3, nh = wid >> 2;
  const int bx = blockIdx.x;
  const float* src; const __hip_bfloat16* W; float* dst = nullptr;
  const float* addb = nullptr; bool bf_out = false;
  long rows0; int nrows;
  if (bx < 391)      { src = i2e; W = wprep + 0 * WCHUNK; bf_out = true; rows0 = (long)bx * 256;         nrows = 100000; }
  else if (bx < 395) { src = t2e; W = wprep + 2 * WCHUNK; dst = Pt;  rows0 = (long)(bx - 391) * 256; nrows = 1000; }
  else if (bx < 396) { src = r2e; W = wprep + 1 * WCHUNK; dst = Pr;  rows0 = 0;                      nrows = 6; addb = ne_b; }
  else if (bx < 436) { src = u2e; W = wprep + 6 * WCHUNK; dst = Pu;  rows0 = (long)(bx - 396) * 256; nrows = 10000; }
  else               { src = u2e; W = wprep + 7 * WCHUNK; dst = Pu2; rows0 = (long)(bx - 436) * 256; nrows = 10000; }

#pragma unroll
  for (int i = 0; i < 4; ++i) {
    int g = tid + i * 512;
    __builtin_amdgcn_global_load_lds(
        (__attribute__((address_space(1))) void*)(void*)(W + g * 8),
        (__attribute__((address_space(3))) void*)(void*)(sW + g * 8), 16, 0, 0);
  }
  const float4* s4 = (const float4*)src;
  const int mr = lane & 15;
  const int rb = m16 * 16 + ((lane >> 4) << 2);

  for (int t = 0; t < 4; ++t) {
    const long r0 = rows0 + t * 64;
#pragma unroll
    for (int i = 0; i < 2; ++i) {
      int g = tid + i * 512;   // 64 rows x 16 kb
      int row = g >> 4, kb = g & 15;
      float4 v0 = {0.f, 0.f, 0.f, 0.f}, v1 = {0.f, 0.f, 0.f, 0.f};
      if (r0 + row < nrows) {
        long base = (r0 + row) * 32 + kb * 2;
        v0 = s4[base]; v1 = s4[base + 1];
      }
      uint4 pk;
      pk.x = ((unsigned)bf_bits(v0.y) << 16) | bf_bits(v0.x);
      pk.y = ((unsigned)bf_bits(v0.w) << 16) | bf_bits(v0.z);
      pk.z = ((unsigned)bf_bits(v1.y) << 16) | bf_bits(v1.x);
      pk.w = ((unsigned)bf_bits(v1.w) << 16) | bf_bits(v1.z);
      *(uint4*)(sA + row * 128 + ((kb ^ (row & 15)) << 3)) = pk;
    }
    __syncthreads();

    f32x4 acc[4];
#pragma unroll
    for (int j = 0; j < 4; ++j) acc[j] = (f32x4){0.f, 0.f, 0.f, 0.f};
    // 16m x 64n single-tile variant via mfma_half2 on (m16, acc pair trick) — do inline:
    {
      const int kq = lane >> 4;
#pragma unroll
      for (int h = 0; h < 2; ++h) {
        const __hip_bfloat16* sWh = sW + h * WHALF;
#pragma unroll
        for (int ks = 0; ks < 2; ++ks) {
          const int kb16 = h * 8 + ks * 4 + kq;
          bf16x8 a = *(const bf16x8*)(sA + (m16 * 16 + mr) * 128 + ((kb16 ^ mr) << 3));
          const int swzb = (((ks * 4 + kq) ^ (mr & 7)) << 3);
#pragma unroll
          for (int nt = 0; nt < 4; ++nt) {
            const int n = nh * 64 + nt * 16 + mr;
            bf16x8 b = *(const bf16x8*)(sWh + n * 64 + swzb);
            acc[nt] = __builtin_amdgcn_mfma_f32_16x16x32_bf16(a, b, acc[nt], 0, 0, 0);
          }
        }
      }
    }
#pragma unroll
    for (int nt = 0; nt < 4; ++nt) {
      const int col = nh * 64 + nt * 16 + mr;
      const float bv = addb ? addb[col] : 0.f;
#pragma unroll
      for (int r = 0; r < 4; ++r) {
        const int row = rb + r;
        if (r0 + row < nrows) {
          if (bf_out) Pi[(r0 + row) * 128 + col] = __float2bfloat16(acc[nt][r]);
          else        dst[(r0 + row) * 128 + col] = acc[nt][r] + bv;
        }
      }
    }
    __syncthreads();   // sA consumed; safe to overwrite next tile
  }
}

// ---------------- main fused kernel: 1 block = 2 users, 2 blocks/CU ----------------
__global__ __launch_bounds__(512, 4) void graphdec_main(
    const __hip_bfloat16* __restrict__ Pi, const float* __restrict__ Pt,
    const float* __restrict__ Pr, const float* __restrict__ Pu,
    const float* __restrict__ Pu2,
    const float* __restrict__ ne1_b, const float* __restrict__ att1_b,
    const float* __restrict__ att2_b, const float* __restrict__ att3_w,
    const float* __restrict__ lin_w, const float* __restrict__ lin_b,
    const float* __restrict__ w1_w, const float* __restrict__ w1_b,
    const float* __restrict__ bn1_g, const float* __restrict__ bn1_b,
    const float* __restrict__ bn1_m, const float* __restrict__ bn1_v,
    const float* __restrict__ w2_w, const float* __restrict__ w2_b,
    const float* __restrict__ bn2_g, const float* __restrict__ bn2_b,
    const float* __restrict__ bn2_m, const float* __restrict__ bn2_v,
    const float* __restrict__ w3_w, const float* __restrict__ w3_b,
    const int* __restrict__ user_idx, const int* __restrict__ item_idx,
    const int* __restrict__ rat_idx, const int* __restrict__ time_idx,
    const __hip_bfloat16* __restrict__ wprep, float* __restrict__ out) {
  __shared__ __align__(16) unsigned char smem[SMEM_TOTAL];
  __hip_bfloat16* sW = (__hip_bfloat16*)(smem + W_OFF);
  __hip_bfloat16* sA = (__hip_bfloat16*)(smem + A_OFF);
  __hip_bfloat16* sX = (__hip_bfloat16*)(smem + X_OFF);
  int*   sIdx   = (int*)  (smem + SMALL);          // 384 ints: [c][u][l]
  float* sUatt  = (float*)(smem + SMALL + 1536);   // 2 x 128 f
  float* sUlin  = (float*)(smem + SMALL + 2560);   // 2 x 128 f
  float* sLP0   = (float*)(smem + SMALL + 3584);   // 128 f (rows 0..127, nh=0)
  float* sLP1   = (float*)(smem + SMALL + 4096);   // 128 f (nh=1)
  // aliases over dead sW (all used only after the last mfma reads of sW)
  float* sPool4 = (float*)(smem + W_OFF);          // 512 f [u][q][d]
  float* sCombP = (float*)(smem + W_OFF + 2048);   // 512 f
  float* sAtt   = (float*)(smem + W_OFF + 4096);   // 128 f (2 users x 64)
  float* sPooled= (float*)(smem + W_OFF + 4608);   // 256 f
  float* sComb  = (float*)(smem + W_OFF + 5632);   // 256 f
  float* sH1    = (float*)(smem + W_OFF + 6656);   // 64 f

  const int tid  = threadIdx.x;
  const int lane = tid & 63;
  const int wid  = tid >> 6;
  const int m32  = wid & 3;   // 32-row group of M=128 (2 users x 64)
  const int nh   = wid >> 2;  // 64-col half of N=128
  const int b    = blockIdx.x;

  // ---- per-lane att3 fragment ----
  float att3r[4];
#pragma unroll
  for (int nt = 0; nt < 4; ++nt) att3r[nt] = att3_w[nh * 64 + nt * 16 + (lane & 15)];

  // ---- preload indices + per-user precomputed vectors ----
  if (tid < 384) {
    int c = tid >> 7, rest = tid & 127, u = rest >> 6, l = rest & 63;
    int v = 0;
    if (l < 50) {
      const int* p = (c == 0) ? item_idx : (c == 1) ? rat_idx : time_idx;
      v = p[(2 * b + u) * 50 + l];
    }
    sIdx[tid] = v;
  }
  {
    int u = tid >> 8, r = tid & 255;
    const long uidu = user_idx[2 * b + u];
    if (r < 128) sUatt[u * 128 + r]         = Pu [uidu * 128 + r];
    else         sUlin[u * 128 + (r - 128)] = Pu2[uidu * 128 + (r - 128)];
  }
  __syncthreads();  // B0

  auto stage16 = [&](const __hip_bfloat16* __restrict__ src) {
#pragma unroll
    for (int i = 0; i < 2; ++i) {
      int g = tid + i * 512;                // 1024 x 16B = 16 KB
      __builtin_amdgcn_global_load_lds(
          (__attribute__((address_space(1))) void*)(void*)(src + g * 8),
          (__attribute__((address_space(3))) void*)(void*)(sW + g * 8), 16, 0, 0);
    }
  };

  f32x4 acc[2][4];
  const f32x4 zf = {0.f, 0.f, 0.f, 0.f};
  auto zacc = [&]() {
#pragma unroll
    for (int i = 0; i < 2; ++i)
#pragma unroll
      for (int j = 0; j < 4; ++j) acc[i][j] = zf;
  };

  // ===== phase 0: stage ne1 h0; x1 = relu(Pi[item]+Pr'[rat]+Pt[time]) -> sA =====
  stage16(wprep + 3 * WCHUNK);
#pragma unroll
  for (int i = 0; i < 4; ++i) {
    int g = tid + i * 512;
    if (g < 1664) {                        // 2 users x 52 rows x 16 kb-blocks
      int u = (g >= 832) ? 1 : 0;
      int gl = g - u * 832;
      int l = gl >> 4, kb = gl & 15;
      uint4 pk = {0u, 0u, 0u, 0u};
      if (l < 50) {
        const bf16x8 pv = *(const bf16x8*)(Pi + (long)sIdx[u * 64 + l] * 128 + kb * 8);
        const float4* pr4 = (const float4*)(Pr + (long)sIdx[128 + u * 64 + l] * 128) + kb * 2;
        const float4* pt4 = (const float4*)(Pt + (long)sIdx[256 + u * 64 + l] * 128) + kb * 2;
        float4 r0 = pr4[0], r1 = pr4[1];
        float4 t0 = pt4[0], t1 = pt4[1];
        float s0 = fmaxf((float)pv[0] + r0.x + t0.x, 0.f);
        float s1 = fmaxf((float)pv[1] + r0.y + t0.y, 0.f);
        float s2 = fmaxf((float)pv[2] + r0.z + t0.z, 0.f);
        float s3 = fmaxf((float)pv[3] + r0.w + t0.w, 0.f);
        float s4 = fmaxf((float)pv[4] + r1.x + t1.x, 0.f);
        float s5 = fmaxf((float)pv[5] + r1.y + t1.y, 0.f);
        float s6 = fmaxf((float)pv[6] + r1.z + t1.z, 0.f);
        float s7 = fmaxf((float)pv[7] + r1.w + t1.w, 0.f);
        pk.x = ((unsigned)bf_bits(s1) << 16) | bf_bits(s0);
        pk.y = ((unsigned)bf_bits(s3) << 16) | bf_bits(s2);
        pk.z = ((unsigned)bf_bits(s5) << 16) | bf_bits(s4);
        pk.w = ((unsigned)bf_bits(s7) << 16) | bf_bits(s6);
      }
      const int row = u * 64 + l;
      *(uint4*)(sA + row * 128 + ((kb ^ (row & 15)) << 3)) = pk;
    }
  }
  __syncthreads();  // B1

  // ===== ne1: x = relu(x1 @ ne1_w + b) =====
  zacc();
  mfma_half2(sA, sW, acc, 0, m32, nh, lane);
  __syncthreads();  // B2
  stage16(wprep + 3 * WCHUNK + WHALF);
  __syncthreads();  // B3
  mfma_half2(sA, sW, acc, 1, m32, nh, lane);
  __syncthreads();  // B4
  stage16(wprep + 4 * WCHUNK);
  epilogue2(acc, ne1_b, nullptr, sX, m32, nh, lane);  // x -> sX
  __syncthreads();  // B5

  // ===== att1: a1 = relu(x @ att1_w[:128] + Pu[u] + b) =====
  zacc();
  mfma_half2(sX, sW, acc, 0, m32, nh, lane);
  __syncthreads();  // B6
  stage16(wprep + 4 * WCHUNK + WHALF);
  __syncthreads();  // B7
  mfma_half2(sX, sW, acc, 1, m32, nh, lane);
  __syncthreads();  // B8
  stage16(wprep + 5 * WCHUNK);
  epilogue2(acc, att1_b, sUatt, sA, m32, nh, lane);   // a1 -> sA
  __syncthreads();  // B9

  // ===== att2 + in-register logits =====
  zacc();
  mfma_half2(sA, sW, acc, 0, m32, nh, lane);
  __syncthreads();  // B10
  stage16(wprep + 5 * WCHUNK + WHALF);
  __syncthreads();  // B11
  mfma_half2(sA, sW, acc, 1, m32, nh, lane);
  {
    float lp[2][4] = {{0.f, 0.f, 0.f, 0.f}, {0.f, 0.f, 0.f, 0.f}};
#pragma unroll
    for (int nt = 0; nt < 4; ++nt) {
      const int col = nh * 64 + nt * 16 + (lane & 15);
      const float b2 = att2_b[col];
#pragma unroll
      for (int mt = 0; mt < 2; ++mt)
#pragma unroll
        for (int r = 0; r < 4; ++r)
          lp[mt][r] += fmaxf(acc[mt][nt][r] + b2, 0.f) * att3r[nt];
    }
#pragma unroll
    for (int off = 1; off < 16; off <<= 1) {
#pragma unroll
      for (int mt = 0; mt < 2; ++mt)
#pragma unroll
        for (int r = 0; r < 4; ++r) lp[mt][r] += __shfl_xor(lp[mt][r], off);
    }
    if ((lane & 15) == 0) {
      float* dst = nh ? sLP1 : sLP0;
#pragma unroll
      for (int mt = 0; mt < 2; ++mt) {
        const int rowb = m32 * 32 + mt * 16 + ((lane >> 4) << 2);
#pragma unroll
        for (int r = 0; r < 4; ++r) dst[rowb + r] = lp[mt][r];
      }
    }
  }
  __syncthreads();  // B12

  // ===== softmax over 50 (waves 0,1 = users 0,1; att3_b cancels) =====
  if (wid < 2) {
    const int u = wid;
    float v = (lane < 50) ? (sLP0[u * 64 + lane] + sLP1[u * 64 + lane]) : -3.4e38f;
    float m = v;
    for (int off = 32; off > 0; off >>= 1) m = fmaxf(m, __shfl_xor(m, off));
    float e = (lane < 50) ? __expf(v - m) : 0.f;
    float s = e;
    for (int off = 32; off > 0; off >>= 1) s += __shfl_xor(s, off);
    sAtt[u * 64 + lane] = e / s;
  }
  __syncthreads();  // B13

  // ===== pooled partials (2 per (u,d)), aliases over dead sW =====
  {
    int u = tid >> 8, q = (tid >> 7) & 1, d = tid & 127;
    const int cblk = d >> 3, clo = d & 7;
    float s = 0.f;
    for (int l = q; l < 50; l += 2) {
      const int row = u * 64 + l;
      s += sAtt[row] * (float)sX[row * 128 + ((cblk ^ (row & 15)) << 3) + clo];
    }
    sPool4[(u * 2 + q) * 128 + d] = s;
  }
  __syncthreads();  // B14
  if (tid < 256) {
    int u = tid >> 7, d = tid & 127;
    sPooled[u * 128 + d] = sPool4[(u * 2) * 128 + d] + sPool4[(u * 2 + 1) * 128 + d];
  }
  __syncthreads();  // B15

  // ===== comb = relu(Pu2[u] + pooled @ lin_w[128:] + lin_b), 2 k-partials =====
  {
    int u = tid >> 8, q = (tid >> 7) & 1, d = tid & 127;
    float s = 0.f;
    for (int j = q * 64; j < q * 64 + 64; ++j)
      s += sPooled[u * 128 + j] * lin_w[(128 + j) * 128 + d];
    sCombP[(u * 2 + q) * 128 + d] = s;
  }
  __syncthreads();  // B16
  if (tid < 256) {
    int u = tid >> 7, d = tid & 127;
    sComb[u * 128 + d] = fmaxf(sCombP[(u * 2) * 128 + d] + sCombP[(u * 2 + 1) * 128 + d]
                               + sUlin[u * 128 + d] + lin_b[d], 0.f);
  }
  __syncthreads();  // B17

  // ===== head: waves 0,1 = users 0,1 =====
  if (wid < 2) {
    const int u = wid;
    if (lane < 32) {
      float s = w1_b[lane];
      for (int k = 0; k < 128; ++k) s += sComb[u * 128 + k] * w1_w[k * 32 + lane];
      s = (s - bn1_m[lane]) * rsqrtf(bn1_v[lane] + 1e-5f) * bn1_g[lane] + bn1_b[lane];
      sH1[u * 32 + lane] = fmaxf(s, 0.f);
    }
    if (lane < 16) {
      float s = w2_b[lane];
      for (int k = 0; k < 32; ++k) s += sH1[u * 32 + k] * w2_w[k * 16 + lane];
      s = (s - bn2_m[lane]) * rsqrtf(bn2_v[lane] + 1e-5f) * bn2_g[lane] + bn2_b[lane];
      float p = fmaxf(s, 0.f) * w3_w[lane];   // relu(h2) then dot w3
      p += __shfl_xor(p, 1); p += __shfl_xor(p, 2);
      p += __shfl_xor(p, 4); p += __shfl_xor(p, 8);
      if (lane == 0) out[2 * b + u] = p + w3_b[0];
    }
  }
}

extern "C" void kernel_launch(void* const* d_in, const int* in_sizes, int n_in,
                              void* d_out, int out_size, void* d_ws, size_t ws_size,
                              hipStream_t stream) {
  const float* u2e    = (const float*)d_in[0];
  const float* i2e    = (const float*)d_in[1];
  const float* r2e    = (const float*)d_in[2];
  const float* t2e    = (const float*)d_in[3];
  const float* ne_w   = (const float*)d_in[4];
  const float* ne_b   = (const float*)d_in[5];
  const float* ne1_w  = (const float*)d_in[6];
  const float* ne1_b  = (const float*)d_in[7];
  const float* att1_w = (const float*)d_in[8];
  const float* att1_b = (const float*)d_in[9];
  const float* att2_w = (const float*)d_in[10];
  const float* att2_b = (const float*)d_in[11];
  const float* att3_w = (const float*)d_in[12];
  const float* att3_b = (const float*)d_in[13];
  const float* lin_w  = (const float*)d_in[14];
  const float* lin_b  = (const float*)d_in[15];
  const float* w1_w   = (const float*)d_in[16];
  const float* w1_b   = (const float*)d_in[17];
  const float* bn1_g  = (const float*)d_in[18];
  const float* bn1_b  = (const float*)d_in[19];
  const float* bn1_m  = (const float*)d_in[20];
  const float* bn1_v  = (const float*)d_in[21];
  const float* w2_w   = (const float*)d_in[22];
  const float* w2_b   = (const float*)d_in[23];
  const float* bn2_g  = (const float*)d_in[24];
  const float* bn2_b  = (const float*)d_in[25];
  const float* bn2_m  = (const float*)d_in[26];
  const float* bn2_v  = (const float*)d_in[27];
  const float* w3_w   = (const float*)d_in[28];
  const float* w3_b   = (const float*)d_in[29];
  const int* user_idx = (const int*)d_in[30];
  const int* item_idx = (const int*)d_in[31];
  const int* rat_idx  = (const int*)d_in[32];
  const int* time_idx = (const int*)d_in[33];
  (void)att3_b;  // constant shift under softmax — cancels

  char* ws = (char*)d_ws;
  __hip_bfloat16* wprep = (__hip_bfloat16*)(ws + WS_WPREP);
  __hip_bfloat16* Pi = (__hip_bfloat16*)(ws + WS_PI);
  float* Pt  = (float*)(ws + WS_PT);
  float* Pr  = (float*)(ws + WS_PR);
  float* Pu  = (float*)(ws + WS_PU);
  float* Pu2 = (float*)(ws + WS_PU2);
  float* out = (float*)d_out;

  prep_weights_kernel<<<32, dim3(64, 4), 0, stream>>>(ne_w, ne1_w, att1_w, att2_w,
                                                      lin_w, wprep);
  pgemm_kernel<<<476, 512, 0, stream>>>(i2e, r2e, t2e, u2e, ne_b, wprep,
                                        Pi, Pt, Pr, Pu, Pu2);
  graphdec_main<<<2048, 512, 0, stream>>>(
      Pi, Pt, Pr, Pu, Pu2, ne1_b, att1_b, att2_b, att3_w,
      lin_w, lin_b, w1_w, w1_b, bn1_g, bn1_b, bn1_m, bn1_v, w2_w, w2_b,
      bn2_g, bn2_b, bn2_m, bn2_v, w3_w, w3_b,
      user_idx, item_idx, rat_idx, time_idx, wprep, out);
}